// Round 14
// baseline (249.038 us; speedup 1.0000x reference)
//
#include <hip/hip_runtime.h>
#include <stdint.h>

#define NROWS 100000
#define SDIM 150
#define HDIM 150
#define NKB 20            // K-steps of 32 (K = 4 segs x 160 padded)
#define BM 64             // rows per block
#define NTHREADS 256      // 4 waves
#define CW 160            // cols per wave (4 waves cover all 640)
#define BSLICE 40960      // bytes per K-step slice of packed W (640 cols * 64B)
#define ASLICE 4096       // A f16 bytes per K-step in LDS (64 rows * 64B)
#define EPIW 648          // epilogue overlay stride in f16

using half8  = __attribute__((ext_vector_type(8))) _Float16;
using fp16x2 = __attribute__((ext_vector_type(2))) __fp16;
using floatx4 = __attribute__((ext_vector_type(4))) float;
using floatx2 = __attribute__((ext_vector_type(2))) float;
using uintx4  = __attribute__((ext_vector_type(4))) unsigned int;

__device__ __forceinline__ float fsig(float x) {
  return __builtin_amdgcn_rcpf(1.0f + __expf(-x));
}
__device__ __forceinline__ float ftanh(float x) {
  return 2.0f * __builtin_amdgcn_rcpf(1.0f + __expf(-2.0f * x)) - 1.0f;
}

// Pack W = [w_in; w_out; u_in; u_out] (600x600 f32) -> f16, k-blocked,
// h-major cols (col = h*4 + g), NO swizzle (consumed from global):
//   byte(col,k) = kb*BSLICE + col*64 + kg*16 + j*2,  kb=k>>5, kg=(k>>3)&3, j=k&7
__global__ void pack_w_kernel(const float* __restrict__ w_in,
                              const float* __restrict__ w_out,
                              const float* __restrict__ u_in,
                              const float* __restrict__ u_out,
                              _Float16* __restrict__ wblk) {
  int idx = blockIdx.x * 256 + threadIdx.x;
  if (idx >= NKB * 640 * 32) return;
  int j   = idx & 7;
  int kg  = (idx >> 3) & 3;
  int col = (idx >> 5) % 640;
  int kb  = idx / (640 * 32);
  int k   = kb * 32 + kg * 8 + j;
  int seg = k / 160;
  int kl  = k - seg * 160;
  int g   = col & 3;         // 0=input 1=output 2=forget 3=update
  int h   = col >> 2;
  float v = 0.0f;
  if (kl < SDIM && h < HDIM) {
    const float* src = (seg == 0) ? w_in : (seg == 1) ? w_out
                     : (seg == 2) ? u_in : u_out;
    v = src[(g * SDIM + kl) * HDIM + h];
  }
  wblk[idx] = (_Float16)v;
}

// Block = 64 rows x 640 cols, 4 waves; wave owns 64 x 160 (acc[4][10]).
// Prologue: ALL of A (64x640 f16, 80KB) staged to LDS once (NONTEMPORAL
// loads: A-stream must not evict packed W from L2); ONE barrier.
// K-loop: 10 B-loads (L2-resident W) + 4 ds_reads + 40 MFMA; no barriers.
// Epilogue streams last_c/outputs with nontemporal ld/st for the same reason.
__global__ __launch_bounds__(NTHREADS, 2) void lstm_fused_kernel(
    const float* __restrict__ s_in, const float* __restrict__ s_out,
    const float* __restrict__ h_in, const float* __restrict__ h_out,
    const float* __restrict__ last_c, const float* __restrict__ bias,
    const _Float16* __restrict__ wblk,
    float* __restrict__ out_hid, float* __restrict__ out_cell) {
  __shared__ __align__(16) char lds[NKB * ASLICE];  // 81920 B (A image; epi aliases)

  const int tid  = threadIdx.x;
  const int lane = tid & 63;
  const int l15  = lane & 15;
  const int kgrp = lane >> 4;
  const int wid  = tid >> 6;           // 0..3
  const int row0 = blockIdx.x * BM;

  const float* segp[4] = {s_in, s_out, h_in, h_out};

  // ---- prologue: stage A[64 rows][640 k] as f16 into LDS, k-blocked ----
  // thread -> row = tid>>2 (0..63), 16B-chunk q = tid&3
  {
    const int a_row = tid >> 2;
    const int a_q   = tid & 3;
    const long n_a  = (long)min(row0 + a_row, NROWS - 1);
    const int a_off = a_row * 64 + ((a_q ^ ((a_row >> 1) & 3)) * 16);
#pragma unroll 5
    for (int kb = 0; kb < NKB; ++kb) {
      const int seg = kb / 5;
      const int kls = (kb % 5) * 32 + a_q * 8;
      floatx4 lo = {0.f, 0.f, 0.f, 0.f};
      floatx4 hi = {0.f, 0.f, 0.f, 0.f};
      const float* p = segp[seg] + (size_t)n_a * SDIM + kls;
      if (kls + 7 < SDIM) {
        lo = __builtin_nontemporal_load((const floatx4*)p);
        hi = __builtin_nontemporal_load((const floatx4*)(p + 4));
      } else if (kls < SDIM) {
        lo = __builtin_nontemporal_load((const floatx4*)p);   // k 144..147
        floatx2 t0 = __builtin_nontemporal_load((const floatx2*)(p + 4));  // k 148,149
        hi[0] = t0[0]; hi[1] = t0[1];
      }
      union { fp16x2 h2[4]; uintx4 u; } pk;
      pk.h2[0] = __builtin_amdgcn_cvt_pkrtz(lo[0], lo[1]);
      pk.h2[1] = __builtin_amdgcn_cvt_pkrtz(lo[2], lo[3]);
      pk.h2[2] = __builtin_amdgcn_cvt_pkrtz(hi[0], hi[1]);
      pk.h2[3] = __builtin_amdgcn_cvt_pkrtz(hi[2], hi[3]);
      *(uintx4*)(lds + kb * ASLICE + a_off) = pk.u;
    }
  }
  __syncthreads();  // A image complete; only barrier before epilogue

  // per-lane A fragment offsets (within one ASLICE)
  int aoff[4];
#pragma unroll
  for (int mt = 0; mt < 4; ++mt) {
    int r = mt * 16 + l15;
    aoff[mt] = r * 64 + ((kgrp ^ ((r >> 1) & 3)) * 16);
  }

  floatx4 acc[4][10] = {};

  // B lane base: byte offset within one K-step slice
  const char* wb = (const char*)wblk + ((wid * CW + l15) * 64 + kgrp * 16);

  // ---- barrier-free K-loop (B loads hit L2-resident W) ----
#pragma unroll 1
  for (int kb = 0; kb < NKB; ++kb) {
    const char* g = wb + (size_t)kb * BSLICE;
    half8 bf0 = *(const half8*)(g);
    half8 bf1 = *(const half8*)(g + 1024);
    half8 bf2 = *(const half8*)(g + 2048);
    half8 bf3 = *(const half8*)(g + 3072);
    half8 bf4 = *(const half8*)(g + 4096);
    half8 bf5 = *(const half8*)(g + 5120);
    half8 bf6 = *(const half8*)(g + 6144);
    half8 bf7 = *(const half8*)(g + 7168);
    half8 bf8 = *(const half8*)(g + 8192);
    half8 bf9 = *(const half8*)(g + 9216);
    const char* ak = lds + kb * ASLICE;
    half8 af0 = *(const half8*)(ak + aoff[0]);
    half8 af1 = *(const half8*)(ak + aoff[1]);
    half8 af2 = *(const half8*)(ak + aoff[2]);
    half8 af3 = *(const half8*)(ak + aoff[3]);
    __builtin_amdgcn_s_setprio(1);
#define MF(MT, AF) \
    acc[MT][0] = __builtin_amdgcn_mfma_f32_16x16x32_f16(AF, bf0, acc[MT][0], 0, 0, 0); \
    acc[MT][1] = __builtin_amdgcn_mfma_f32_16x16x32_f16(AF, bf1, acc[MT][1], 0, 0, 0); \
    acc[MT][2] = __builtin_amdgcn_mfma_f32_16x16x32_f16(AF, bf2, acc[MT][2], 0, 0, 0); \
    acc[MT][3] = __builtin_amdgcn_mfma_f32_16x16x32_f16(AF, bf3, acc[MT][3], 0, 0, 0); \
    acc[MT][4] = __builtin_amdgcn_mfma_f32_16x16x32_f16(AF, bf4, acc[MT][4], 0, 0, 0); \
    acc[MT][5] = __builtin_amdgcn_mfma_f32_16x16x32_f16(AF, bf5, acc[MT][5], 0, 0, 0); \
    acc[MT][6] = __builtin_amdgcn_mfma_f32_16x16x32_f16(AF, bf6, acc[MT][6], 0, 0, 0); \
    acc[MT][7] = __builtin_amdgcn_mfma_f32_16x16x32_f16(AF, bf7, acc[MT][7], 0, 0, 0); \
    acc[MT][8] = __builtin_amdgcn_mfma_f32_16x16x32_f16(AF, bf8, acc[MT][8], 0, 0, 0); \
    acc[MT][9] = __builtin_amdgcn_mfma_f32_16x16x32_f16(AF, bf9, acc[MT][9], 0, 0, 0);
    MF(0, af0)
    MF(1, af1)
    MF(2, af2)
    MF(3, af3)
#undef MF
    __builtin_amdgcn_s_setprio(0);
  }

  // ---- bias fragments ----
  float bfrag[10];
#pragma unroll
  for (int nf = 0; nf < 10; ++nf) {
    int bcol = wid * CW + nf * 16 + l15;
    int bh = bcol >> 2, bg = bcol & 3;
    bfrag[nf] = (bh < HDIM) ? bias[bg * HDIM + bh] : 0.f;
  }

  // ---- epilogue: 4 chunks of 16 rows (chunk c = acc[c]); overlay aliases A ----
  _Float16* epi = (_Float16*)lds;  // 16 * 648 * 2 = 20736 B
#pragma unroll
  for (int c = 0; c < 4; ++c) {
    __syncthreads();  // A reads (c=0) / previous chunk consume done
#pragma unroll
    for (int nf = 0; nf < 10; ++nf) {
      int colb = wid * CW + nf * 16 + l15;
#pragma unroll
      for (int i = 0; i < 4; ++i) {
        // C/D layout: col = lane&15, row = (lane>>4)*4 + i  (rows c*16..c*16+15)
        int rl = kgrp * 4 + i;
        epi[rl * EPIW + colb] = (_Float16)fsig(acc[c][nf][i] + bfrag[nf]);
      }
    }
    __syncthreads();
    // consume: idx -> (row, h-pair); 75 consecutive threads = one 600B row
#pragma unroll
    for (int it = 0; it < 5; ++it) {
      int idx = tid + it * NTHREADS;
      if (idx < 16 * 75) {
        int row = idx / 75;
        int h2  = idx - row * 75;
        long nrow = (long)row0 + c * 16 + row;
        if (nrow < NROWS) {
          int h = h2 * 2;
          union { uintx4 u; _Float16 f[8]; } gg;  // [i,o,f,u]@h, [i,o,f,u]@h+1
          gg.u = *(const uintx4*)(epi + row * EPIW + h2 * 8);
          floatx2 lc = __builtin_nontemporal_load(
              (const floatx2*)(last_c + (size_t)nrow * HDIM + h));
          float c0 = (float)gg.f[2] * lc[0] + (float)gg.f[3] * (float)gg.f[0];
          float c1 = (float)gg.f[6] * lc[1] + (float)gg.f[7] * (float)gg.f[4];
          float hd0 = (float)gg.f[1] * ftanh(c0);
          float hd1 = (float)gg.f[5] * ftanh(c1);
          floatx2 oh = {hd0, hd1};
          floatx2 oc = {c0, c1};
          __builtin_nontemporal_store(oh,
              (floatx2*)(out_hid + (size_t)nrow * HDIM + h));
          __builtin_nontemporal_store(oc,
              (floatx2*)(out_cell + (size_t)nrow * HDIM + h));
        }
      }
    }
  }
}

extern "C" void kernel_launch(void* const* d_in, const int* in_sizes, int n_in,
                              void* d_out, int out_size, void* d_ws, size_t ws_size,
                              hipStream_t stream) {
  const float* s_in   = (const float*)d_in[0];
  const float* s_out  = (const float*)d_in[1];
  const float* h_in   = (const float*)d_in[2];
  const float* h_out  = (const float*)d_in[3];
  const float* last_c = (const float*)d_in[4];
  const float* w_in   = (const float*)d_in[5];
  const float* w_out  = (const float*)d_in[6];
  const float* u_in   = (const float*)d_in[7];
  const float* u_out  = (const float*)d_in[8];
  const float* b      = (const float*)d_in[9];

  _Float16* wblk = (_Float16*)d_ws;  // 819200 B

  pack_w_kernel<<<(NKB * 640 * 32 + 255) / 256, 256, 0, stream>>>(
      w_in, w_out, u_in, u_out, wblk);

  float* out_hid  = (float*)d_out;
  float* out_cell = out_hid + (size_t)NROWS * HDIM;

  const int nrb = (NROWS + BM - 1) / BM;  // 1563
  lstm_fused_kernel<<<nrb, NTHREADS, 0, stream>>>(
      s_in, s_out, h_in, h_out, last_c, b, wblk, out_hid, out_cell);
}